// Round 4
// baseline (4104.204 us; speedup 1.0000x reference)
//
#include <hip/hip_runtime.h>
#include <hip/hip_bf16.h>
#include <stdint.h>

#define BATCH   128
#define LPAST   365
#define DIN     32
#define HHOR    8
#define NSTAT   27
#define HID     1024
#define TEMBN   256
#define TSTEPS  372      // LPAST + HHOR - 1
#define NPAST   364      // past steps (LPAST - 1)
#define INDIM   60
#define KF      64       // padded feats width

#define NPAIR   4        // CU pairs-of-groups
#define CUPP    64       // CUs per pair (each CU serves 2 groups of 16 batches)

typedef _Float16 f16_t;
typedef f16_t   f16x8 __attribute__((ext_vector_type(8)));
typedef float   f32x4 __attribute__((ext_vector_type(4)));
typedef uint32_t u32x4 __attribute__((ext_vector_type(4)));

__device__ __forceinline__ f32x4 mfma16(f16x8 a, f16x8 b, f32x4 c) {
    return __builtin_amdgcn_mfma_f32_16x16x32_f16(a, b, c, 0, 0, 0);
}
__device__ __forceinline__ float sigm(float x) { return 1.f / (1.f + expf(-x)); }

// 20-load prefetch for one set: 16 h chunks (sc1, MALL) + 4 feats frags (cached)
#define PF20(o0,o1,o2,o3,o4,o5,o6,o7,o8,o9,o10,o11,o12,o13,o14,o15,e0,e1,e2,e3,pH,pL,pFH,pFL) \
  asm volatile( \
    "global_load_dwordx4 %0,  %20, off sc1\n\t" \
    "global_load_dwordx4 %1,  %20, off offset:256 sc1\n\t" \
    "global_load_dwordx4 %2,  %20, off offset:512 sc1\n\t" \
    "global_load_dwordx4 %3,  %20, off offset:768 sc1\n\t" \
    "global_load_dwordx4 %4,  %20, off offset:1024 sc1\n\t" \
    "global_load_dwordx4 %5,  %20, off offset:1280 sc1\n\t" \
    "global_load_dwordx4 %6,  %20, off offset:1536 sc1\n\t" \
    "global_load_dwordx4 %7,  %20, off offset:1792 sc1\n\t" \
    "global_load_dwordx4 %8,  %21, off sc1\n\t" \
    "global_load_dwordx4 %9,  %21, off offset:256 sc1\n\t" \
    "global_load_dwordx4 %10, %21, off offset:512 sc1\n\t" \
    "global_load_dwordx4 %11, %21, off offset:768 sc1\n\t" \
    "global_load_dwordx4 %12, %21, off offset:1024 sc1\n\t" \
    "global_load_dwordx4 %13, %21, off offset:1280 sc1\n\t" \
    "global_load_dwordx4 %14, %21, off offset:1536 sc1\n\t" \
    "global_load_dwordx4 %15, %21, off offset:1792 sc1\n\t" \
    "global_load_dwordx4 %16, %22, off\n\t" \
    "global_load_dwordx4 %17, %22, off offset:64\n\t" \
    "global_load_dwordx4 %18, %23, off\n\t" \
    "global_load_dwordx4 %19, %23, off offset:64" \
    : "=&v"(o0),"=&v"(o1),"=&v"(o2),"=&v"(o3),"=&v"(o4),"=&v"(o5),"=&v"(o6),"=&v"(o7), \
      "=&v"(o8),"=&v"(o9),"=&v"(o10),"=&v"(o11),"=&v"(o12),"=&v"(o13),"=&v"(o14),"=&v"(o15), \
      "=&v"(e0),"=&v"(e1),"=&v"(e2),"=&v"(e3) \
    : "v"(pH), "v"(pL), "v"(pFH), "v"(pFL) : "memory")

// wait: N older loads may stay outstanding; ties the 20 regs so uses can't move above
#define WAITVM(N,o0,o1,o2,o3,o4,o5,o6,o7,o8,o9,o10,o11,o12,o13,o14,o15,e0,e1,e2,e3) \
  asm volatile("s_waitcnt vmcnt(" #N ")" \
    : "+v"(o0),"+v"(o1),"+v"(o2),"+v"(o3),"+v"(o4),"+v"(o5),"+v"(o6),"+v"(o7), \
      "+v"(o8),"+v"(o9),"+v"(o10),"+v"(o11),"+v"(o12),"+v"(o13),"+v"(o14),"+v"(o15), \
      "+v"(e0),"+v"(e1),"+v"(e2),"+v"(e3) :: )

// barrier that waits LDS only -- leaves vector-memory prefetch in flight
#define LGKBAR() asm volatile("s_waitcnt lgkmcnt(0)\n\ts_barrier" ::: "memory")

// ---------------- prologue: build feats hi/lo fp16 planes [2][B][T][KF] ----
__global__ __launch_bounds__(256)
void build_feats(const float* __restrict__ xp, const float* __restrict__ nf,
                 const float* __restrict__ xf, const float* __restrict__ st,
                 f16_t* __restrict__ feats)
{
    int idx = blockIdx.x * 256 + threadIdx.x;
    if (idx >= BATCH * TSTEPS * KF) return;
    int k  = idx & (KF - 1);
    int bt = idx >> 6;
    int t  = bt % TSTEPS;
    int b  = bt / TSTEPS;
    float v = 0.f;
    if (k < DIN) {
        v = (t < LPAST) ? xp[((size_t)b * LPAST + t) * DIN + k]
                        : xf[((size_t)b * (HHOR - 1) + (t - LPAST)) * DIN + k];
    } else if (k == DIN) {
        v = (t >= NPAST) ? nf[b * HHOR + (t - NPAST)] : 0.f;
    } else if (k < DIN + 1 + NSTAT) {
        v = st[b * NSTAT + (k - DIN - 1)];
    }
    f16_t hi = (f16_t)v;
    f16_t lo = (f16_t)(v - (float)hi);
    feats[idx] = hi;
    feats[(size_t)BATCH * TSTEPS * KF + idx] = lo;
}

// ---------------- prologue: time-embedding MLP (fp32) ----------------
__global__ __launch_bounds__(256)
void time_mlp(const float* __restrict__ tv, const float* __restrict__ freqs,
              const float* __restrict__ phases,
              const float* __restrict__ W1, const float* __restrict__ b1,
              const float* __restrict__ W2, const float* __restrict__ b2,
              float* __restrict__ temb)
{
    __shared__ float emb[TEMBN];
    __shared__ float hmid[2 * TEMBN];
    int b = blockIdx.x, tid = threadIdx.x;
    float t = tv[b];
    {
        float x = t * freqs[tid] + phases[tid];
        emb[tid] = cosf(x) * 1.41421356237309515f;
    }
    __syncthreads();
    for (int j = tid; j < 2 * TEMBN; j += 256) {
        float s = b1[j];
        const float* wr = W1 + (size_t)j * TEMBN;
        for (int k = 0; k < TEMBN; k++) s += wr[k] * emb[k];
        hmid[j] = s / (1.f + expf(-s));   // SiLU
    }
    __syncthreads();
    for (int j = tid; j < HID; j += 256) {
        float s = b2[j];
        const float* wr = W2 + (size_t)j * (2 * TEMBN);
        for (int k = 0; k < 2 * TEMBN; k++) s += wr[k] * hmid[k];
        temb[(size_t)b * HID + j] = s;
    }
}

// ---------------- main persistent dual-set LSTM kernel ----------------
__global__ __launch_bounds__(256, 1)
void lstm_persist(const f16_t* __restrict__ feats,
                  const float* __restrict__ temb,
                  f16_t* hbuf, float* hfut, uint32_t* flags,
                  const float* __restrict__ W_ih, const float* __restrict__ W_hh,
                  const float* __restrict__ b_ih, const float* __restrict__ b_hh)
{
    // stg: fragment-major h staging (shared sequentially by the two sets).
    // slot p (16B) = col*16 + row  (col = k-chunk 0..127, row = batch 0..15)
    // gbuf oversized so total LDS (83968 B) > 80 KiB -> exactly 1 WG/CU.
    __shared__ __align__(16) f16_t stg[2][16384];          // [plane][slots]
    __shared__ __align__(16) float gbuf[2 * 1280 + 2048];  // [khalf][64 rows x 20]

    const int tid  = threadIdx.x;
    const int w    = tid >> 6;
    const int lane = tid & 63;
    const int q    = lane >> 4;
    const int n15  = lane & 15;
    const int hf   = w >> 1;          // K-half (0: k<512, 1: k>=512)
    const int rg   = w & 1;           // row group (32 rows each)
    const int P    = blockIdx.x & 3;  // pair id
    const int m    = blockIdx.x >> 2; // member CU 0..63
    const int gA   = P * 2;           // set-A group (batches gA*16..)
    const int gB   = P * 2 + 1;

    // ---- persistent weight fragments ----
    f16x8 Bhh[2][16];                 // [nt][kt]  rows rg*32+nt*16+n15, K-half hf
    f16x8 BihH[2][2], BihL[2][2];
#pragma unroll
    for (int nt = 0; nt < 2; nt++) {
        const int rho  = rg * 32 + nt * 16 + n15;
        const int grow = (rho >> 4) * HID + m * 16 + (rho & 15);
        const float* wr = W_hh + (size_t)grow * HID + hf * 512;
#pragma unroll
        for (int kt = 0; kt < 16; kt++) {
            const float* s = wr + kt * 32 + q * 8;
            f16x8 f;
#pragma unroll
            for (int j = 0; j < 8; j++) f[j] = (f16_t)s[j];
            Bhh[nt][kt] = f;
        }
        const float* wr2 = W_ih + (size_t)grow * INDIM;
#pragma unroll
        for (int kt = 0; kt < 2; kt++) {
            f16x8 fh, fl;
#pragma unroll
            for (int j = 0; j < 8; j++) {
                int k = kt * 32 + q * 8 + j;
                float v = (k < INDIM) ? wr2[k] : 0.f;
                f16_t h = (f16_t)v;
                fh[j] = h;
                fl[j] = (f16_t)(v - (float)h);
            }
            BihH[kt ? 1 : 0][0] = BihH[kt ? 1 : 0][0]; // no-op to appease unroll
            BihH[nt][kt] = fh;
            BihL[nt][kt] = fl;
        }
    }

    // ---- elementwise ownership: 1 (unit,batch) per thread per set ----
    const int ue  = tid & 15;          // unit within CU slice
    const int be  = tid >> 4;          // batch within group
    const int U   = m * 16 + ue;       // global hidden unit
    const int gbatA = gA * 16 + be, gbatB = gB * 16 + be;
    float bias[4];
#pragma unroll
    for (int g4 = 0; g4 < 4; g4++)
        bias[g4] = b_ih[g4 * HID + U] + b_hh[g4 * HID + U];
    float cA = 0.f, cB = 0.f;

    const size_t HPAR   = (size_t)2 * BATCH * HID;   // f16 per parity (2 planes)
    const size_t HPLANE = (size_t)BATCH * HID;
    const size_t FPLANE = (size_t)BATCH * TSTEPS * KF;
    uint32_t* pflags = flags + (size_t)P * CUPP;

    // staging-load per-thread sub-offset (row=tid&15 of group slab, col base tid>>4)
    const int stSub = (tid & 15) * 2048 + (tid >> 4) * 16;   // bytes
    const int ldsW  = tid * 16;                              // LDS write base bytes (x16 per slot)

    u32x4 aH0,aH1,aH2,aH3,aH4,aH5,aH6,aH7, aL0,aL1,aL2,aL3,aL4,aL5,aL6,aL7, aF0,aF1,aF2,aF3;
    u32x4 bH0,bH1,bH2,bH3,bH4,bH5,bH6,bH7, bL0,bL1,bL2,bL3,bL4,bL5,bL6,bL7, bF0,bF1,bF2,bF3;

    // ---- initial prefetch for t=0 (h parity-0 buffer pre-zeroed) ----
    {
        const char* pH = (const char*)(hbuf) + ((size_t)gA * 16 * HID) * 2 + stSub;
        const char* pL = pH + HPLANE * 2;
        const char* fH = (const char*)feats + (((size_t)(gA * 16 + n15) * TSTEPS + 0) * KF + q * 8) * 2;
        const char* fL = fH + FPLANE * 2;
        PF20(aH0,aH1,aH2,aH3,aH4,aH5,aH6,aH7,aL0,aL1,aL2,aL3,aL4,aL5,aL6,aL7,aF0,aF1,aF2,aF3,pH,pL,fH,fL);
        const char* pH2 = (const char*)(hbuf) + ((size_t)gB * 16 * HID) * 2 + stSub;
        const char* pL2 = pH2 + HPLANE * 2;
        const char* fH2 = (const char*)feats + (((size_t)(gB * 16 + n15) * TSTEPS + 0) * KF + q * 8) * 2;
        const char* fL2 = fH2 + FPLANE * 2;
        PF20(bH0,bH1,bH2,bH3,bH4,bH5,bH6,bH7,bL0,bL1,bL2,bL3,bL4,bL5,bL6,bL7,bF0,bF1,bF2,bF3,pH2,pL2,fH2,fL2);
    }

#pragma unroll 1
    for (int t = 0; t < TSTEPS; t++) {
        // ================= SET A =================
        WAITVM(20, aH0,aH1,aH2,aH3,aH4,aH5,aH6,aH7,aL0,aL1,aL2,aL3,aL4,aL5,aL6,aL7,aF0,aF1,aF2,aF3);
        {   // stage into fragment-major LDS (wave-linear, conflict-free)
            u32x4 DH[8] = {aH0,aH1,aH2,aH3,aH4,aH5,aH6,aH7};
            u32x4 DL[8] = {aL0,aL1,aL2,aL3,aL4,aL5,aL6,aL7};
#pragma unroll
            for (int i = 0; i < 8; i++) {
                *(u32x4*)((char*)&stg[0][0] + ldsW + i * 4096) = DH[i];
                *(u32x4*)((char*)&stg[1][0] + ldsW + i * 4096) = DL[i];
            }
        }
        LGKBAR();
        f32x4 acc0 = {0.f,0.f,0.f,0.f}, acc1 = {0.f,0.f,0.f,0.f};
        if (hf == 0) {   // input projection (K=60) only on K-half-0 waves
            f16x8 fH0 = __builtin_bit_cast(f16x8, aF0), fH1 = __builtin_bit_cast(f16x8, aF1);
            f16x8 fL0 = __builtin_bit_cast(f16x8, aF2), fL1 = __builtin_bit_cast(f16x8, aF3);
            acc0 = mfma16(fH0, BihH[0][0], acc0); acc0 = mfma16(fH1, BihH[0][1], acc0);
            acc0 = mfma16(fH0, BihL[0][0], acc0); acc0 = mfma16(fH1, BihL[0][1], acc0);
            acc0 = mfma16(fL0, BihH[0][0], acc0); acc0 = mfma16(fL1, BihH[0][1], acc0);
            acc1 = mfma16(fH0, BihH[1][0], acc1); acc1 = mfma16(fH1, BihH[1][1], acc1);
            acc1 = mfma16(fH0, BihL[1][0], acc1); acc1 = mfma16(fH1, BihL[1][1], acc1);
            acc1 = mfma16(fL0, BihH[1][0], acc1); acc1 = mfma16(fL1, BihH[1][1], acc1);
        }
        {
            const char* sH = (const char*)&stg[0][0] + hf * 16384 + q * 256 + n15 * 16;
            const char* sL = (const char*)&stg[1][0] + hf * 16384 + q * 256 + n15 * 16;
#pragma unroll
            for (int kt = 0; kt < 16; kt++) {
                f16x8 ah = __builtin_bit_cast(f16x8, *(const u32x4*)(sH + kt * 1024));
                f16x8 al = __builtin_bit_cast(f16x8, *(const u32x4*)(sL + kt * 1024));
                acc0 = mfma16(ah, Bhh[0][kt], acc0);
                acc1 = mfma16(ah, Bhh[1][kt], acc1);
                acc0 = mfma16(al, Bhh[0][kt], acc0);
                acc1 = mfma16(al, Bhh[1][kt], acc1);
            }
            *(f32x4*)(&gbuf[hf * 1280 + (rg * 32 + n15) * 20 + q * 4])      = acc0;
            *(f32x4*)(&gbuf[hf * 1280 + (rg * 32 + 16 + n15) * 20 + q * 4]) = acc1;
        }
        LGKBAR();
        {   // elementwise A
            int a0 = ue * 20 + be;
            float xi = gbuf[a0]        + gbuf[1280 + a0]        + bias[0];
            float xf = gbuf[a0 + 320]  + gbuf[1280 + a0 + 320]  + bias[1];
            float xg = gbuf[a0 + 640]  + gbuf[1280 + a0 + 640]  + bias[2];
            float xo = gbuf[a0 + 960]  + gbuf[1280 + a0 + 960]  + bias[3];
            cA = sigm(xf) * cA + sigm(xi) * tanhf(xg);
            float hv = sigm(xo) * tanhf(cA);
            if (t == NPAST - 1) { float tv = temb[(size_t)gbatA * HID + U]; hv += tv; cA += tv; }
            f16_t hh = (f16_t)hv; f16_t hl = (f16_t)(hv - (float)hh);
            char* sA = (char*)hbuf + (((size_t)((t + 1) & 1)) * HPAR + (size_t)gbatA * HID + U) * 2;
            char* sA2 = sA + HPLANE * 2;
            asm volatile("global_store_short %0, %2, off sc1\n\t"
                         "global_store_short %1, %3, off sc1"
                         :: "v"(sA), "v"(sA2),
                            "v"((uint32_t)__builtin_bit_cast(uint16_t, hh)),
                            "v"((uint32_t)__builtin_bit_cast(uint16_t, hl)) : "memory");
            if (t >= NPAST) {
                float* hp = hfut + ((size_t)(t - NPAST) * BATCH + gbatA) * HID + U;
                asm volatile("global_store_dword %0, %1, off" :: "v"(hp), "v"(hv) : "memory");
            }
        }
        // ================= SET B =================
        WAITVM(2, bH0,bH1,bH2,bH3,bH4,bH5,bH6,bH7,bL0,bL1,bL2,bL3,bL4,bL5,bL6,bL7,bF0,bF1,bF2,bF3);
        {
            u32x4 DH[8] = {bH0,bH1,bH2,bH3,bH4,bH5,bH6,bH7};
            u32x4 DL[8] = {bL0,bL1,bL2,bL3,bL4,bL5,bL6,bL7};
#pragma unroll
            for (int i = 0; i < 8; i++) {
                *(u32x4*)((char*)&stg[0][0] + ldsW + i * 4096) = DH[i];
                *(u32x4*)((char*)&stg[1][0] + ldsW + i * 4096) = DL[i];
            }
        }
        LGKBAR();
        f32x4 bcc0 = {0.f,0.f,0.f,0.f}, bcc1 = {0.f,0.f,0.f,0.f};
        if (hf == 0) {
            f16x8 fH0 = __builtin_bit_cast(f16x8, bF0), fH1 = __builtin_bit_cast(f16x8, bF1);
            f16x8 fL0 = __builtin_bit_cast(f16x8, bF2), fL1 = __builtin_bit_cast(f16x8, bF3);
            bcc0 = mfma16(fH0, BihH[0][0], bcc0); bcc0 = mfma16(fH1, BihH[0][1], bcc0);
            bcc0 = mfma16(fH0, BihL[0][0], bcc0); bcc0 = mfma16(fH1, BihL[0][1], bcc0);
            bcc0 = mfma16(fL0, BihH[0][0], bcc0); bcc0 = mfma16(fL1, BihH[0][1], bcc0);
            bcc1 = mfma16(fH0, BihH[1][0], bcc1); bcc1 = mfma16(fH1, BihH[1][1], bcc1);
            bcc1 = mfma16(fH0, BihL[1][0], bcc1); bcc1 = mfma16(fH1, BihL[1][1], bcc1);
            bcc1 = mfma16(fL0, BihH[1][0], bcc1); bcc1 = mfma16(fL1, BihH[1][1], bcc1);
        }
        {
            const char* sH = (const char*)&stg[0][0] + hf * 16384 + q * 256 + n15 * 16;
            const char* sL = (const char*)&stg[1][0] + hf * 16384 + q * 256 + n15 * 16;
#pragma unroll
            for (int kt = 0; kt < 16; kt++) {
                f16x8 ah = __builtin_bit_cast(f16x8, *(const u32x4*)(sH + kt * 1024));
                f16x8 al = __builtin_bit_cast(f16x8, *(const u32x4*)(sL + kt * 1024));
                bcc0 = mfma16(ah, Bhh[0][kt], bcc0);
                bcc1 = mfma16(ah, Bhh[1][kt], bcc1);
                bcc0 = mfma16(al, Bhh[0][kt], bcc0);
                bcc1 = mfma16(al, Bhh[1][kt], bcc1);
            }
            *(f32x4*)(&gbuf[hf * 1280 + (rg * 32 + n15) * 20 + q * 4])      = bcc0;
            *(f32x4*)(&gbuf[hf * 1280 + (rg * 32 + 16 + n15) * 20 + q * 4]) = bcc1;
        }
        LGKBAR();
        {   // elementwise B
            int a0 = ue * 20 + be;
            float xi = gbuf[a0]        + gbuf[1280 + a0]        + bias[0];
            float xf = gbuf[a0 + 320]  + gbuf[1280 + a0 + 320]  + bias[1];
            float xg = gbuf[a0 + 640]  + gbuf[1280 + a0 + 640]  + bias[2];
            float xo = gbuf[a0 + 960]  + gbuf[1280 + a0 + 960]  + bias[3];
            cB = sigm(xf) * cB + sigm(xi) * tanhf(xg);
            float hv = sigm(xo) * tanhf(cB);
            if (t == NPAST - 1) { float tv = temb[(size_t)gbatB * HID + U]; hv += tv; cB += tv; }
            f16_t hh = (f16_t)hv; f16_t hl = (f16_t)(hv - (float)hh);
            char* sB = (char*)hbuf + (((size_t)((t + 1) & 1)) * HPAR + (size_t)gbatB * HID + U) * 2;
            char* sB2 = sB + HPLANE * 2;
            asm volatile("global_store_short %0, %2, off sc1\n\t"
                         "global_store_short %1, %3, off sc1"
                         :: "v"(sB), "v"(sB2),
                            "v"((uint32_t)__builtin_bit_cast(uint16_t, hh)),
                            "v"((uint32_t)__builtin_bit_cast(uint16_t, hl)) : "memory");
            if (t >= NPAST) {
                float* hp = hfut + ((size_t)(t - NPAST) * BATCH + gbatB) * HID + U;
                asm volatile("global_store_dword %0, %1, off" :: "v"(hp), "v"(hv) : "memory");
            }
        }

        // ---- publish + group barrier (queues empty after this syncthreads) ----
        __syncthreads();   // drains vmcnt(0): all h stores visible at MALL
        if (tid == 0)
            __hip_atomic_store(&pflags[m], (uint32_t)(t + 1),
                               __ATOMIC_RELAXED, __HIP_MEMORY_SCOPE_AGENT);
        if (w == 0) {      // wave 0 polls all 64 member flags
            uint32_t tgt = (uint32_t)(t + 1);
            for (;;) {
                uint32_t v = __hip_atomic_load(&pflags[lane],
                                               __ATOMIC_RELAXED, __HIP_MEMORY_SCOPE_AGENT);
                if (__all(v >= tgt)) break;
            }
        }
        __syncthreads();

        // ---- prefetch next step (both sets), left in flight across loop edge ----
        {
            int tn = (t + 1 < TSTEPS) ? t + 1 : t;   // last-iter: harmless re-read
            size_t hpar = (size_t)(tn & 1) * HPAR;
            const char* pH = (const char*)(hbuf) + (hpar + (size_t)gA * 16 * HID) * 2 + stSub;
            const char* pL = pH + HPLANE * 2;
            const char* fH = (const char*)feats + (((size_t)(gA * 16 + n15) * TSTEPS + tn) * KF + q * 8) * 2;
            const char* fL = fH + FPLANE * 2;
            PF20(aH0,aH1,aH2,aH3,aH4,aH5,aH6,aH7,aL0,aL1,aL2,aL3,aL4,aL5,aL6,aL7,aF0,aF1,aF2,aF3,pH,pL,fH,fL);
            const char* pH2 = (const char*)(hbuf) + (hpar + (size_t)gB * 16 * HID) * 2 + stSub;
            const char* pL2 = pH2 + HPLANE * 2;
            const char* fH2 = (const char*)feats + (((size_t)(gB * 16 + n15) * TSTEPS + tn) * KF + q * 8) * 2;
            const char* fL2 = fH2 + FPLANE * 2;
            PF20(bH0,bH1,bH2,bH3,bH4,bH5,bH6,bH7,bL0,bL1,bL2,bL3,bL4,bL5,bL6,bL7,bF0,bF1,bF2,bF3,pH2,pL2,fH2,fL2);
        }
    }
    asm volatile("s_waitcnt vmcnt(0)" ::: "memory");   // drain before endpgm
}

// ---------------- epilogue: head out[b,s] = h . Wh + bh ----------------
__global__ __launch_bounds__(256)
void head(const float* __restrict__ hfut, const float* __restrict__ Wh,
          const float* __restrict__ bh, float* __restrict__ out)
{
    int b = blockIdx.x >> 3, s = blockIdx.x & 7;
    int tid = threadIdx.x;
    const float* h = hfut + ((size_t)s * BATCH + b) * HID;
    float4 hv = *(const float4*)(h + tid * 4);
    float4 wv = *(const float4*)(Wh + tid * 4);
    float p = hv.x * wv.x + hv.y * wv.y + hv.z * wv.z + hv.w * wv.w;
#pragma unroll
    for (int off = 32; off > 0; off >>= 1) p += __shfl_down(p, off);
    __shared__ float r[4];
    if ((tid & 63) == 0) r[tid >> 6] = p;
    __syncthreads();
    if (tid == 0) out[b * HHOR + s] = r[0] + r[1] + r[2] + r[3] + bh[0];
}

extern "C" void kernel_launch(void* const* d_in, const int* in_sizes, int n_in,
                              void* d_out, int out_size, void* d_ws, size_t ws_size,
                              hipStream_t stream)
{
    const float* x_past = (const float*)d_in[0];
    const float* noisy  = (const float*)d_in[1];
    const float* tv     = (const float*)d_in[2];
    const float* x_fut  = (const float*)d_in[3];
    const float* statc  = (const float*)d_in[4];
    const float* W_ih   = (const float*)d_in[5];
    const float* W_hh   = (const float*)d_in[6];
    const float* b_ih   = (const float*)d_in[7];
    const float* b_hh   = (const float*)d_in[8];
    const float* freqs  = (const float*)d_in[9];
    const float* phases = (const float*)d_in[10];
    const float* W1     = (const float*)d_in[11];
    const float* b1     = (const float*)d_in[12];
    const float* W2     = (const float*)d_in[13];
    const float* b2     = (const float*)d_in[14];
    const float* Wh     = (const float*)d_in[15];
    const float* bh     = (const float*)d_in[16];
    float* out = (float*)d_out;

    char* ws = (char*)d_ws;
    const size_t sz_feats = (size_t)2 * BATCH * TSTEPS * KF * 2;   // 2 planes
    const size_t off_temb = sz_feats;
    const size_t sz_temb  = (size_t)BATCH * HID * 4;
    const size_t off_hbuf = off_temb + sz_temb;
    const size_t sz_hbuf  = (size_t)2 * 2 * BATCH * HID * 2;       // 2 par x 2 planes
    const size_t off_hfut = off_hbuf + sz_hbuf;
    const size_t sz_hfut  = (size_t)HHOR * BATCH * HID * 4;
    const size_t off_flag = off_hfut + sz_hfut;

    f16_t*    feats = (f16_t*)(ws);
    float*    temb  = (float*)(ws + off_temb);
    f16_t*    hbuf  = (f16_t*)(ws + off_hbuf);
    float*    hfut  = (float*)(ws + off_hfut);
    uint32_t* flags = (uint32_t*)(ws + off_flag);

    // zero h parity-0 (both planes) and the per-CU flags
    hipMemsetAsync(hbuf, 0, (size_t)2 * BATCH * HID * 2, stream);
    hipMemsetAsync(flags, 0, (size_t)NPAIR * CUPP * sizeof(uint32_t), stream);

    build_feats<<<(BATCH * TSTEPS * KF) / 256, 256, 0, stream>>>(x_past, noisy, x_fut, statc, feats);
    time_mlp<<<BATCH, 256, 0, stream>>>(tv, freqs, phases, W1, b1, W2, b2, temb);
    lstm_persist<<<NPAIR * CUPP, 256, 0, stream>>>(feats, temb, hbuf, hfut, flags,
                                                   W_ih, W_hh, b_ih, b_hh);
    head<<<BATCH * HHOR, 256, 0, stream>>>(hfut, Wh, bh, out);
}

// Round 5
// 2290.840 us; speedup vs baseline: 1.7916x; 1.7916x over previous
//
#include <hip/hip_runtime.h>
#include <hip/hip_bf16.h>
#include <stdint.h>

#define BATCH   128
#define LPAST   365
#define DIN     32
#define HHOR    8
#define NSTAT   27
#define HID     1024
#define TEMBN   256
#define TSTEPS  372      // LPAST + HHOR - 1
#define NPAST   364      // past steps (LPAST - 1)
#define INDIM   60
#define KF      64       // padded feats width

#define NGRP    8        // batch groups (32 consumer CUs each -- keep!)
#define CUPG    32
#define BPG     16

typedef _Float16 f16_t;
typedef f16_t   f16x8 __attribute__((ext_vector_type(8)));
typedef float   f32x4 __attribute__((ext_vector_type(4)));
typedef uint32_t u32x4 __attribute__((ext_vector_type(4)));

__device__ __forceinline__ f32x4 mfma16(f16x8 a, f16x8 b, f32x4 c) {
    return __builtin_amdgcn_mfma_f32_16x16x32_f16(a, b, c, 0, 0, 0);
}
__device__ __forceinline__ float sigm(float x) { return 1.f / (1.f + expf(-x)); }

// ---------------- prologue: build feats hi/lo fp16 planes [2][B][T][KF] ----
__global__ __launch_bounds__(256)
void build_feats(const float* __restrict__ xp, const float* __restrict__ nf,
                 const float* __restrict__ xf, const float* __restrict__ st,
                 f16_t* __restrict__ feats)
{
    int idx = blockIdx.x * 256 + threadIdx.x;
    if (idx >= BATCH * TSTEPS * KF) return;
    int k  = idx & (KF - 1);
    int bt = idx >> 6;
    int t  = bt % TSTEPS;
    int b  = bt / TSTEPS;
    float v = 0.f;
    if (k < DIN) {
        v = (t < LPAST) ? xp[((size_t)b * LPAST + t) * DIN + k]
                        : xf[((size_t)b * (HHOR - 1) + (t - LPAST)) * DIN + k];
    } else if (k == DIN) {
        v = (t >= NPAST) ? nf[b * HHOR + (t - NPAST)] : 0.f;
    } else if (k < DIN + 1 + NSTAT) {
        v = st[b * NSTAT + (k - DIN - 1)];
    }
    f16_t hi = (f16_t)v;
    f16_t lo = (f16_t)(v - (float)hi);
    feats[idx] = hi;
    feats[(size_t)BATCH * TSTEPS * KF + idx] = lo;
}

// ---------------- prologue: time-embedding MLP (fp32) ----------------
__global__ __launch_bounds__(256)
void time_mlp(const float* __restrict__ tv, const float* __restrict__ freqs,
              const float* __restrict__ phases,
              const float* __restrict__ W1, const float* __restrict__ b1,
              const float* __restrict__ W2, const float* __restrict__ b2,
              float* __restrict__ temb)
{
    __shared__ float emb[TEMBN];
    __shared__ float hmid[2 * TEMBN];
    int b = blockIdx.x, tid = threadIdx.x;
    float t = tv[b];
    {
        float x = t * freqs[tid] + phases[tid];
        emb[tid] = cosf(x) * 1.41421356237309515f;
    }
    __syncthreads();
    for (int j = tid; j < 2 * TEMBN; j += 256) {
        float s = b1[j];
        const float* wr = W1 + (size_t)j * TEMBN;
        for (int k = 0; k < TEMBN; k++) s += wr[k] * emb[k];
        hmid[j] = s / (1.f + expf(-s));   // SiLU
    }
    __syncthreads();
    for (int j = tid; j < HID; j += 256) {
        float s = b2[j];
        const float* wr = W2 + (size_t)j * (2 * TEMBN);
        for (int k = 0; k < 2 * TEMBN; k++) s += wr[k] * hmid[k];
        temb[(size_t)b * HID + j] = s;
    }
}

// ---------------- main persistent LSTM kernel ----------------
// hbuf layout (f16): [parity][plane][group][16384]
//   slot within group slab: f = kchunk*128 + batch*8 + e   (kchunk=k>>3, e=k&7)
// so consumers stage with LINEAR tid*16 loads and wave-linear LDS writes,
// and A-frag LDS reads are the conflict-free fragment-major pattern.
#define HPAR   262144   // f16 per parity  (2 planes x 8 groups x 16384)
#define HPLN   131072   // f16 per plane   (8 groups x 16384)
#define GSLAB  16384    // f16 per group slab

__global__ __launch_bounds__(256, 1)
void lstm_persist(const f16_t* __restrict__ feats,
                  const float* __restrict__ temb,
                  f16_t* hbuf, float* hfut, uint32_t* flags,
                  const float* __restrict__ W_ih, const float* __restrict__ W_hh,
                  const float* __restrict__ b_ih, const float* __restrict__ b_hh)
{
    // stg: fragment-major h staging (identical flat copy of the group slab).
    // 64 KB + 24 KB gbuf = 88 KB > 80 KB -> exactly 1 WG/CU.
    __shared__ __align__(16) f16_t stg[2][GSLAB];           // [plane][16384]
    __shared__ __align__(16) float gbuf[2 * 2560 + 1024];   // [khalf][128 rows x 20]

    const int tid  = threadIdx.x;
    const int w    = tid >> 6;
    const int lane = tid & 63;
    const int q    = lane >> 4;
    const int n15  = lane & 15;
    const int hf   = w >> 1;          // K-half (0: k<512, 1: k>=512)
    const int rg   = w & 1;           // row group (64 of 128 4H-rows)
    const int g    = blockIdx.x & 7;  // group (XCD-locality heuristic)
    const int m    = blockIdx.x >> 3; // member CU within group, 0..31

    // ---- persistent weight fragments (fp16) ----
    f16x8 Bhh[4][16];                 // [nt][kt]: rows rg*64+nt*16+n15, K-half hf
    f16x8 BihH[4][2], BihL[4][2];     // input weights (used by hf==0 waves)
#pragma unroll
    for (int nt = 0; nt < 4; nt++) {
        const int rho  = rg * 64 + nt * 16 + n15;            // 4H-row in CU slice
        const int grow = (rho >> 5) * HID + m * 32 + (rho & 31);
        const float* wr = W_hh + (size_t)grow * HID + hf * 512;
#pragma unroll
        for (int kt = 0; kt < 16; kt++) {
            const float* s = wr + kt * 32 + q * 8;
            f16x8 f;
#pragma unroll
            for (int j = 0; j < 8; j++) f[j] = (f16_t)s[j];
            Bhh[nt][kt] = f;
        }
        const float* wr2 = W_ih + (size_t)grow * INDIM;
#pragma unroll
        for (int kt = 0; kt < 2; kt++) {
            f16x8 fh, fl;
#pragma unroll
            for (int j = 0; j < 8; j++) {
                int k = kt * 32 + q * 8 + j;
                float v = (k < INDIM) ? wr2[k] : 0.f;
                f16_t h = (f16_t)v;
                fh[j] = h;
                fl[j] = (f16_t)(v - (float)h);
            }
            BihH[nt][kt] = fh;
            BihL[nt][kt] = fl;
        }
    }

    // ---- elementwise ownership: 2 (unit,batch) pairs per thread ----
    const int p0  = tid * 2;
    const int eb  = p0 >> 5;          // batch in group, 0..15
    const int eu0 = p0 & 31;          // even local unit
    const int gb  = g * BPG + eb;     // global batch
    const int U0  = m * 32 + eu0;     // global hidden unit
    const int a0  = eu0 * 20 + eb;    // gbuf row base
    float bias0[4], bias1[4];
#pragma unroll
    for (int gg = 0; gg < 4; gg++) {
        bias0[gg] = b_ih[gg * HID + U0]     + b_hh[gg * HID + U0];
        bias1[gg] = b_ih[gg * HID + U0 + 1] + b_hh[gg * HID + U0 + 1];
    }
    float c0 = 0.f, c1 = 0.f;

    uint32_t* gflags = flags + (size_t)g * CUPG;
    const size_t FPLANE = (size_t)BATCH * TSTEPS * KF;   // feats plane stride
    // producer store offset within slab (f16 units), covers U0,U0+1 as dword
    const int stOff = (U0 >> 3) * 128 + eb * 8 + (U0 & 7);

#pragma unroll 1
    for (int t = 0; t < TSTEPS; t++) {
        // ---- feats A-fragments, hi+lo (plain loads, cached) ----
        const f16_t* fr = feats + ((size_t)(g * BPG + n15) * TSTEPS + t) * KF + q * 8;
        u32x4 fuH0 = *(const u32x4*)(fr);
        u32x4 fuH1 = *(const u32x4*)(fr + 32);
        u32x4 fuL0 = *(const u32x4*)(fr + FPLANE);
        u32x4 fuL1 = *(const u32x4*)(fr + FPLANE + 32);

        // ---- stage h (hi/lo) -- LINEAR sc1 loads, wave-linear LDS writes ----
        {
            const f16_t* srcH = hbuf + (size_t)(t & 1) * HPAR + (size_t)g * GSLAB;
            const f16_t* srcL = srcH + HPLN;
            const char* bH = (const char*)srcH + tid * 16 + 2048;
            const char* bL = (const char*)srcL + tid * 16 + 2048;
            const char* aH0 = bH;            const char* aL0 = bL;
            const char* aH1 = bH + 8192;     const char* aL1 = bL + 8192;
            const char* aH2 = bH + 16384;    const char* aL2 = bL + 16384;
            const char* aH3 = bH + 24576;    const char* aL3 = bL + 24576;
            u32x4 dh0, dh1, dh2, dh3, dh4, dh5, dh6, dh7;
            u32x4 dl0, dl1, dl2, dl3, dl4, dl5, dl6, dl7;
            asm volatile(
                "global_load_dwordx4 %0,  %16, off offset:-2048 sc1\n\t"
                "global_load_dwordx4 %1,  %16, off offset:2048  sc1\n\t"
                "global_load_dwordx4 %2,  %17, off offset:-2048 sc1\n\t"
                "global_load_dwordx4 %3,  %17, off offset:2048  sc1\n\t"
                "global_load_dwordx4 %4,  %18, off offset:-2048 sc1\n\t"
                "global_load_dwordx4 %5,  %18, off offset:2048  sc1\n\t"
                "global_load_dwordx4 %6,  %19, off offset:-2048 sc1\n\t"
                "global_load_dwordx4 %7,  %19, off offset:2048  sc1\n\t"
                "global_load_dwordx4 %8,  %20, off offset:-2048 sc1\n\t"
                "global_load_dwordx4 %9,  %20, off offset:2048  sc1\n\t"
                "global_load_dwordx4 %10, %21, off offset:-2048 sc1\n\t"
                "global_load_dwordx4 %11, %21, off offset:2048  sc1\n\t"
                "global_load_dwordx4 %12, %22, off offset:-2048 sc1\n\t"
                "global_load_dwordx4 %13, %22, off offset:2048  sc1\n\t"
                "global_load_dwordx4 %14, %23, off offset:-2048 sc1\n\t"
                "global_load_dwordx4 %15, %23, off offset:2048  sc1\n\t"
                "s_waitcnt vmcnt(0)"
                : "=&v"(dh0), "=&v"(dh1), "=&v"(dh2), "=&v"(dh3),
                  "=&v"(dh4), "=&v"(dh5), "=&v"(dh6), "=&v"(dh7),
                  "=&v"(dl0), "=&v"(dl1), "=&v"(dl2), "=&v"(dl3),
                  "=&v"(dl4), "=&v"(dl5), "=&v"(dl6), "=&v"(dl7)
                : "v"(aH0), "v"(aH1), "v"(aH2), "v"(aH3),
                  "v"(aL0), "v"(aL1), "v"(aL2), "v"(aL3)
                : "memory");
            u32x4 DH[8] = {dh0, dh1, dh2, dh3, dh4, dh5, dh6, dh7};
            u32x4 DL[8] = {dl0, dl1, dl2, dl3, dl4, dl5, dl6, dl7};
#pragma unroll
            for (int i = 0; i < 8; i++) {
                *(u32x4*)((char*)&stg[0][0] + tid * 16 + i * 4096) = DH[i];
                *(u32x4*)((char*)&stg[1][0] + tid * 16 + i * 4096) = DL[i];
            }
        }

        // ---- input-projection MFMAs (hf==0 waves; no LDS dependency) ----
        f32x4 acc[4];
#pragma unroll
        for (int nt = 0; nt < 4; nt++) acc[nt] = (f32x4){0.f, 0.f, 0.f, 0.f};
        if (hf == 0) {
            f16x8 fH0 = __builtin_bit_cast(f16x8, fuH0);
            f16x8 fH1 = __builtin_bit_cast(f16x8, fuH1);
            f16x8 fL0 = __builtin_bit_cast(f16x8, fuL0);
            f16x8 fL1 = __builtin_bit_cast(f16x8, fuL1);
#pragma unroll
            for (int nt = 0; nt < 4; nt++) {
                acc[nt] = mfma16(fH0, BihH[nt][0], acc[nt]);
                acc[nt] = mfma16(fH1, BihH[nt][1], acc[nt]);
                acc[nt] = mfma16(fH0, BihL[nt][0], acc[nt]);
                acc[nt] = mfma16(fH1, BihL[nt][1], acc[nt]);
                acc[nt] = mfma16(fL0, BihH[nt][0], acc[nt]);
                acc[nt] = mfma16(fL1, BihH[nt][1], acc[nt]);
            }
        }
        __syncthreads();   // staging visible

        // ---- recurrent MFMAs over this wave's K-half (conflict-free b128) ----
        {
            const char* sH = (const char*)&stg[0][0] + hf * 16384 + q * 256 + n15 * 16;
            const char* sL = (const char*)&stg[1][0] + hf * 16384 + q * 256 + n15 * 16;
#pragma unroll
            for (int kt = 0; kt < 16; kt++) {
                f16x8 ah = __builtin_bit_cast(f16x8, *(const u32x4*)(sH + kt * 1024));
                f16x8 al = __builtin_bit_cast(f16x8, *(const u32x4*)(sL + kt * 1024));
#pragma unroll
                for (int nt = 0; nt < 4; nt++) {
                    acc[nt] = mfma16(ah, Bhh[nt][kt], acc[nt]);
                    acc[nt] = mfma16(al, Bhh[nt][kt], acc[nt]);
                }
            }
#pragma unroll
            for (int nt = 0; nt < 4; nt++)
                *(f32x4*)(&gbuf[hf * 2560 + (rg * 64 + nt * 16 + n15) * 20 + q * 4]) = acc[nt];
        }
        __syncthreads();

        // ---- elementwise LSTM cell (fp32), 2 pairs per thread ----
        float xi0 = gbuf[a0]        + gbuf[2560 + a0]        + bias0[0];
        float xf0 = gbuf[a0 + 640]  + gbuf[2560 + a0 + 640]  + bias0[1];
        float xg0 = gbuf[a0 + 1280] + gbuf[2560 + a0 + 1280] + bias0[2];
        float xo0 = gbuf[a0 + 1920] + gbuf[2560 + a0 + 1920] + bias0[3];
        c0 = sigm(xf0) * c0 + sigm(xi0) * tanhf(xg0);
        float h0v = sigm(xo0) * tanhf(c0);

        float xi1 = gbuf[a0 + 20]        + gbuf[2560 + a0 + 20]        + bias1[0];
        float xf1 = gbuf[a0 + 20 + 640]  + gbuf[2560 + a0 + 20 + 640]  + bias1[1];
        float xg1 = gbuf[a0 + 20 + 1280] + gbuf[2560 + a0 + 20 + 1280] + bias1[2];
        float xo1 = gbuf[a0 + 20 + 1920] + gbuf[2560 + a0 + 20 + 1920] + bias1[3];
        c1 = sigm(xf1) * c1 + sigm(xi1) * tanhf(xg1);
        float h1v = sigm(xo1) * tanhf(c1);

        if (t == NPAST - 1) {   // boundary: h0 = h_p + temb, c0 = c_p + temb
            float t0 = temb[(size_t)gb * HID + U0];
            float t1 = temb[(size_t)gb * HID + U0 + 1];
            h0v += t0; c0 += t0;
            h1v += t1; c1 += t1;
        }
        if (t >= NPAST) {       // future pass: store fp32 h for head
            float* hp = hfut + ((size_t)(t - NPAST) * BATCH + gb) * HID;
            hp[U0]     = h0v;
            hp[U0 + 1] = h1v;
        }

        // ---- broadcast new h (hi/lo fp16) in fragment-major slab order ----
        {
            f16_t h0h = (f16_t)h0v; f16_t h0l = (f16_t)(h0v - (float)h0h);
            f16_t h1h = (f16_t)h1v; f16_t h1l = (f16_t)(h1v - (float)h1h);
            uint32_t ph = (uint32_t)__builtin_bit_cast(uint16_t, h0h)
                        | ((uint32_t)__builtin_bit_cast(uint16_t, h1h) << 16);
            uint32_t pl = (uint32_t)__builtin_bit_cast(uint16_t, h0l)
                        | ((uint32_t)__builtin_bit_cast(uint16_t, h1l) << 16);
            f16_t* dst = hbuf + (size_t)((t + 1) & 1) * HPAR + (size_t)g * GSLAB + stOff;
            __hip_atomic_store((uint32_t*)dst, ph,
                               __ATOMIC_RELAXED, __HIP_MEMORY_SCOPE_AGENT);
            __hip_atomic_store((uint32_t*)(dst + HPLN), pl,
                               __ATOMIC_RELAXED, __HIP_MEMORY_SCOPE_AGENT);
        }

        // ---- per-group flag barrier (no fences, no L2 maintenance) ----
        __syncthreads();   // drains vmcnt(0): all sc1 stores visible at MALL
        if (tid == 0)
            __hip_atomic_store(&gflags[m], (uint32_t)(t + 1),
                               __ATOMIC_RELAXED, __HIP_MEMORY_SCOPE_AGENT);
        if (w == 0) {      // wave 0 polls all 32 member flags
            uint32_t tgt = (uint32_t)(t + 1);
            for (;;) {
                uint32_t v = tgt;
                if (lane < CUPG)
                    v = __hip_atomic_load(&gflags[lane],
                                          __ATOMIC_RELAXED, __HIP_MEMORY_SCOPE_AGENT);
                if (__all(v >= tgt)) break;
            }
        }
        __syncthreads();
    }
}

// ---------------- epilogue: head out[b,s] = h . Wh + bh ----------------
__global__ __launch_bounds__(256)
void head(const float* __restrict__ hfut, const float* __restrict__ Wh,
          const float* __restrict__ bh, float* __restrict__ out)
{
    int b = blockIdx.x >> 3, s = blockIdx.x & 7;
    int tid = threadIdx.x;
    const float* h = hfut + ((size_t)s * BATCH + b) * HID;
    float4 hv = *(const float4*)(h + tid * 4);
    float4 wv = *(const float4*)(Wh + tid * 4);
    float p = hv.x * wv.x + hv.y * wv.y + hv.z * wv.z + hv.w * wv.w;
#pragma unroll
    for (int off = 32; off > 0; off >>= 1) p += __shfl_down(p, off);
    __shared__ float r[4];
    if ((tid & 63) == 0) r[tid >> 6] = p;
    __syncthreads();
    if (tid == 0) out[b * HHOR + s] = r[0] + r[1] + r[2] + r[3] + bh[0];
}

extern "C" void kernel_launch(void* const* d_in, const int* in_sizes, int n_in,
                              void* d_out, int out_size, void* d_ws, size_t ws_size,
                              hipStream_t stream)
{
    const float* x_past = (const float*)d_in[0];
    const float* noisy  = (const float*)d_in[1];
    const float* tv     = (const float*)d_in[2];
    const float* x_fut  = (const float*)d_in[3];
    const float* statc  = (const float*)d_in[4];
    const float* W_ih   = (const float*)d_in[5];
    const float* W_hh   = (const float*)d_in[6];
    const float* b_ih   = (const float*)d_in[7];
    const float* b_hh   = (const float*)d_in[8];
    const float* freqs  = (const float*)d_in[9];
    const float* phases = (const float*)d_in[10];
    const float* W1     = (const float*)d_in[11];
    const float* b1     = (const float*)d_in[12];
    const float* W2     = (const float*)d_in[13];
    const float* b2     = (const float*)d_in[14];
    const float* Wh     = (const float*)d_in[15];
    const float* bh     = (const float*)d_in[16];
    float* out = (float*)d_out;

    char* ws = (char*)d_ws;
    const size_t sz_feats = (size_t)2 * BATCH * TSTEPS * KF * 2;   // 2 planes
    const size_t off_temb = sz_feats;
    const size_t sz_temb  = (size_t)BATCH * HID * 4;
    const size_t off_hbuf = off_temb + sz_temb;
    const size_t sz_hbuf  = (size_t)2 * HPAR * 2;                  // 2 parities
    const size_t off_hfut = off_hbuf + sz_hbuf;
    const size_t sz_hfut  = (size_t)HHOR * BATCH * HID * 4;
    const size_t off_flag = off_hfut + sz_hfut;

    f16_t*    feats = (f16_t*)(ws);
    float*    temb  = (float*)(ws + off_temb);
    f16_t*    hbuf  = (f16_t*)(ws + off_hbuf);
    float*    hfut  = (float*)(ws + off_hfut);
    uint32_t* flags = (uint32_t*)(ws + off_flag);

    // zero h parity-0 (both planes, all groups) and the per-CU flags
    hipMemsetAsync(hbuf, 0, (size_t)HPAR * 2, stream);
    hipMemsetAsync(flags, 0, (size_t)NGRP * CUPG * sizeof(uint32_t), stream);

    build_feats<<<(BATCH * TSTEPS * KF) / 256, 256, 0, stream>>>(x_past, noisy, x_fut, statc, feats);
    time_mlp<<<BATCH, 256, 0, stream>>>(tv, freqs, phases, W1, b1, W2, b2, temb);
    lstm_persist<<<NGRP * CUPG, 256, 0, stream>>>(feats, temb, hbuf, hfut, flags,
                                                  W_ih, W_hh, b_ih, b_hh);
    head<<<BATCH * HHOR, 256, 0, stream>>>(hfut, Wh, bh, out);
}

// Round 7
// 2137.328 us; speedup vs baseline: 1.9203x; 1.0718x over previous
//
#include <hip/hip_runtime.h>
#include <hip/hip_bf16.h>
#include <stdint.h>

#define BATCH   128
#define LPAST   365
#define DIN     32
#define HHOR    8
#define NSTAT   27
#define HID     1024
#define TEMBN   256
#define TSTEPS  372      // LPAST + HHOR - 1
#define NPAST   364      // past steps (LPAST - 1)
#define INDIM   60
#define KF      64       // padded feats width

#define NGRP    8        // batch groups == physical XCDs
#define CUPG    32
#define BPG     16

typedef _Float16 f16_t;
typedef f16_t   f16x8 __attribute__((ext_vector_type(8)));
typedef float   f32x4 __attribute__((ext_vector_type(4)));
typedef uint32_t u32x4 __attribute__((ext_vector_type(4)));

__device__ __forceinline__ f32x4 mfma16(f16x8 a, f16x8 b, f32x4 c) {
    return __builtin_amdgcn_mfma_f32_16x16x32_f16(a, b, c, 0, 0, 0);
}
__device__ __forceinline__ float sigm(float x) { return 1.f / (1.f + expf(-x)); }

// ---------------- prologue: build feats hi/lo fp16 planes [2][B][T][KF] ----
__global__ __launch_bounds__(256)
void build_feats(const float* __restrict__ xp, const float* __restrict__ nf,
                 const float* __restrict__ xf, const float* __restrict__ st,
                 f16_t* __restrict__ feats)
{
    int idx = blockIdx.x * 256 + threadIdx.x;
    if (idx >= BATCH * TSTEPS * KF) return;
    int k  = idx & (KF - 1);
    int bt = idx >> 6;
    int t  = bt % TSTEPS;
    int b  = bt / TSTEPS;
    float v = 0.f;
    if (k < DIN) {
        v = (t < LPAST) ? xp[((size_t)b * LPAST + t) * DIN + k]
                        : xf[((size_t)b * (HHOR - 1) + (t - LPAST)) * DIN + k];
    } else if (k == DIN) {
        v = (t >= NPAST) ? nf[b * HHOR + (t - NPAST)] : 0.f;
    } else if (k < DIN + 1 + NSTAT) {
        v = st[b * NSTAT + (k - DIN - 1)];
    }
    f16_t hi = (f16_t)v;
    f16_t lo = (f16_t)(v - (float)hi);
    feats[idx] = hi;
    feats[(size_t)BATCH * TSTEPS * KF + idx] = lo;
}

// ---------------- prologue: time-embedding MLP (fp32) ----------------
__global__ __launch_bounds__(256)
void time_mlp(const float* __restrict__ tv, const float* __restrict__ freqs,
              const float* __restrict__ phases,
              const float* __restrict__ W1, const float* __restrict__ b1,
              const float* __restrict__ W2, const float* __restrict__ b2,
              float* __restrict__ temb)
{
    __shared__ float emb[TEMBN];
    __shared__ float hmid[2 * TEMBN];
    int b = blockIdx.x, tid = threadIdx.x;
    float t = tv[b];
    {
        float x = t * freqs[tid] + phases[tid];
        emb[tid] = cosf(x) * 1.41421356237309515f;
    }
    __syncthreads();
    for (int j = tid; j < 2 * TEMBN; j += 256) {
        float s = b1[j];
        const float* wr = W1 + (size_t)j * TEMBN;
        for (int k = 0; k < TEMBN; k++) s += wr[k] * emb[k];
        hmid[j] = s / (1.f + expf(-s));   // SiLU
    }
    __syncthreads();
    for (int j = tid; j < HID; j += 256) {
        float s = b2[j];
        const float* wr = W2 + (size_t)j * (2 * TEMBN);
        for (int k = 0; k < 2 * TEMBN; k++) s += wr[k] * hmid[k];
        temb[(size_t)b * HID + j] = s;
    }
}

// ---------------- main persistent LSTM kernel ----------------
// Groups bound to PHYSICAL XCDs via s_getreg(HW_REG_XCC_ID) + atomic slot
// claim (88KB LDS => 1 WG/CU => each XCD hosts exactly its 32 CUs' WGs).
// h exchange is XCD-local: sc0 (SE-scope) stores drain to the XCD's L2 before
// vmcnt retires; sc0 loads bypass L1 and hit that L2. Barrier flags use the
// proven device-scope (sc1) path from rounds 3/5 — their traffic is trivial.
// hbuf layout (f16): [parity][plane][group][16384], fragment-major slab:
//   slot = kchunk*128 + batch*8 + (k&7)
#define HPAR   262144   // f16 per parity  (2 planes x 8 groups x 16384)
#define HPLN   131072   // f16 per plane   (8 groups x 16384)
#define GSLAB  16384    // f16 per group slab

__global__ __launch_bounds__(256, 1)
void lstm_persist(const f16_t* __restrict__ feats,
                  const float* __restrict__ temb,
                  f16_t* hbuf, float* hfut, uint32_t* flags, int* cnts,
                  const float* __restrict__ W_ih, const float* __restrict__ W_hh,
                  const float* __restrict__ b_ih, const float* __restrict__ b_hh)
{
    __shared__ __align__(16) f16_t stg[2][GSLAB];           // 64 KB
    __shared__ __align__(16) float gbuf[2 * 2560 + 1024];   // ~24 KB -> 1 WG/CU
    __shared__ int claimLds[2];

    const int tid  = threadIdx.x;
    const int w    = tid >> 6;
    const int lane = tid & 63;
    const int q    = lane >> 4;
    const int n15  = lane & 15;
    const int hf   = w >> 1;          // K-half (0: k<512, 1: k>=512)
    const int rg   = w & 1;           // row group (64 of 128 4H-rows)

    // ---- claim (group = physical XCD, member = claimed slot) ----
    {
        int xcd = __builtin_amdgcn_s_getreg((3 << 11) | 20) & 7;  // HW_REG_XCC_ID
        if (tid == 0) {
            int slot = atomicAdd(&cnts[xcd], 1);
            claimLds[0] = xcd;
            claimLds[1] = slot;
        }
    }
    __syncthreads();
    const int g = claimLds[0];
    const int m = claimLds[1] & 31;   // &31: degrade (not hang) if claim breaks

    // ---- persistent weight fragments (fp16) ----
    f16x8 Bhh[4][16];                 // [nt][kt]: rows rg*64+nt*16+n15, K-half hf
    f16x8 BihH[4][2], BihL[4][2];     // input weights (used by hf==0 waves)
#pragma unroll
    for (int nt = 0; nt < 4; nt++) {
        const int rho  = rg * 64 + nt * 16 + n15;            // 4H-row in CU slice
        const int grow = (rho >> 5) * HID + m * 32 + (rho & 31);
        const float* wr = W_hh + (size_t)grow * HID + hf * 512;
#pragma unroll
        for (int kt = 0; kt < 16; kt++) {
            const float* s = wr + kt * 32 + q * 8;
            f16x8 f;
#pragma unroll
            for (int j = 0; j < 8; j++) f[j] = (f16_t)s[j];
            Bhh[nt][kt] = f;
        }
        const float* wr2 = W_ih + (size_t)grow * INDIM;
#pragma unroll
        for (int kt = 0; kt < 2; kt++) {
            f16x8 fh, fl;
#pragma unroll
            for (int j = 0; j < 8; j++) {
                int k = kt * 32 + q * 8 + j;
                float v = (k < INDIM) ? wr2[k] : 0.f;
                f16_t h = (f16_t)v;
                fh[j] = h;
                fl[j] = (f16_t)(v - (float)h);
            }
            BihH[nt][kt] = fh;
            BihL[nt][kt] = fl;
        }
    }

    // ---- elementwise ownership: 2 (unit,batch) pairs per thread ----
    const int p0  = tid * 2;
    const int eb  = p0 >> 5;          // batch in group, 0..15
    const int eu0 = p0 & 31;          // even local unit
    const int gb  = g * BPG + eb;     // global batch
    const int U0  = m * 32 + eu0;     // global hidden unit
    const int a0  = eu0 * 20 + eb;    // gbuf row base
    float bias0[4], bias1[4];
#pragma unroll
    for (int gg = 0; gg < 4; gg++) {
        bias0[gg] = b_ih[gg * HID + U0]     + b_hh[gg * HID + U0];
        bias1[gg] = b_ih[gg * HID + U0 + 1] + b_hh[gg * HID + U0 + 1];
    }
    float c0 = 0.f, c1 = 0.f;

    uint32_t* gflags = flags + (size_t)g * CUPG;
    const size_t FPLANE = (size_t)BATCH * TSTEPS * KF;   // feats plane stride
    // producer store offset within slab (f16 units), covers U0,U0+1 as dword
    const int stOff = (U0 >> 3) * 128 + eb * 8 + (U0 & 7);

#pragma unroll 1
    for (int t = 0; t < TSTEPS; t++) {
        // ---- feats A-fragments, hi+lo (plain loads, cached) ----
        const f16_t* fr = feats + ((size_t)(g * BPG + n15) * TSTEPS + t) * KF + q * 8;
        u32x4 fuH0 = *(const u32x4*)(fr);
        u32x4 fuH1 = *(const u32x4*)(fr + 32);
        u32x4 fuL0 = *(const u32x4*)(fr + FPLANE);
        u32x4 fuL1 = *(const u32x4*)(fr + FPLANE + 32);

        // ---- stage h (hi/lo): LINEAR sc0 (XCD-L2) loads, wave-linear LDS writes ----
        {
            const f16_t* srcH = hbuf + (size_t)(t & 1) * HPAR + (size_t)g * GSLAB;
            const f16_t* srcL = srcH + HPLN;
            const char* bH = (const char*)srcH + tid * 16 + 2048;
            const char* bL = (const char*)srcL + tid * 16 + 2048;
            const char* aH0 = bH;            const char* aL0 = bL;
            const char* aH1 = bH + 8192;     const char* aL1 = bL + 8192;
            const char* aH2 = bH + 16384;    const char* aL2 = bL + 16384;
            const char* aH3 = bH + 24576;    const char* aL3 = bL + 24576;
            u32x4 dh0, dh1, dh2, dh3, dh4, dh5, dh6, dh7;
            u32x4 dl0, dl1, dl2, dl3, dl4, dl5, dl6, dl7;
            asm volatile(
                "global_load_dwordx4 %0,  %16, off offset:-2048 sc0\n\t"
                "global_load_dwordx4 %1,  %16, off offset:2048  sc0\n\t"
                "global_load_dwordx4 %2,  %17, off offset:-2048 sc0\n\t"
                "global_load_dwordx4 %3,  %17, off offset:2048  sc0\n\t"
                "global_load_dwordx4 %4,  %18, off offset:-2048 sc0\n\t"
                "global_load_dwordx4 %5,  %18, off offset:2048  sc0\n\t"
                "global_load_dwordx4 %6,  %19, off offset:-2048 sc0\n\t"
                "global_load_dwordx4 %7,  %19, off offset:2048  sc0\n\t"
                "global_load_dwordx4 %8,  %20, off offset:-2048 sc0\n\t"
                "global_load_dwordx4 %9,  %20, off offset:2048  sc0\n\t"
                "global_load_dwordx4 %10, %21, off offset:-2048 sc0\n\t"
                "global_load_dwordx4 %11, %21, off offset:2048  sc0\n\t"
                "global_load_dwordx4 %12, %22, off offset:-2048 sc0\n\t"
                "global_load_dwordx4 %13, %22, off offset:2048  sc0\n\t"
                "global_load_dwordx4 %14, %23, off offset:-2048 sc0\n\t"
                "global_load_dwordx4 %15, %23, off offset:2048  sc0\n\t"
                "s_waitcnt vmcnt(0)"
                : "=&v"(dh0), "=&v"(dh1), "=&v"(dh2), "=&v"(dh3),
                  "=&v"(dh4), "=&v"(dh5), "=&v"(dh6), "=&v"(dh7),
                  "=&v"(dl0), "=&v"(dl1), "=&v"(dl2), "=&v"(dl3),
                  "=&v"(dl4), "=&v"(dl5), "=&v"(dl6), "=&v"(dl7)
                : "v"(aH0), "v"(aH1), "v"(aH2), "v"(aH3),
                  "v"(aL0), "v"(aL1), "v"(aL2), "v"(aL3)
                : "memory");
            u32x4 DH[8] = {dh0, dh1, dh2, dh3, dh4, dh5, dh6, dh7};
            u32x4 DL[8] = {dl0, dl1, dl2, dl3, dl4, dl5, dl6, dl7};
#pragma unroll
            for (int i = 0; i < 8; i++) {
                *(u32x4*)((char*)&stg[0][0] + tid * 16 + i * 4096) = DH[i];
                *(u32x4*)((char*)&stg[1][0] + tid * 16 + i * 4096) = DL[i];
            }
        }

        // ---- input-projection MFMAs (hf==0 waves; no LDS dependency) ----
        f32x4 acc[4];
#pragma unroll
        for (int nt = 0; nt < 4; nt++) acc[nt] = (f32x4){0.f, 0.f, 0.f, 0.f};
        if (hf == 0) {
            f16x8 fH0 = __builtin_bit_cast(f16x8, fuH0);
            f16x8 fH1 = __builtin_bit_cast(f16x8, fuH1);
            f16x8 fL0 = __builtin_bit_cast(f16x8, fuL0);
            f16x8 fL1 = __builtin_bit_cast(f16x8, fuL1);
#pragma unroll
            for (int nt = 0; nt < 4; nt++) {
                acc[nt] = mfma16(fH0, BihH[nt][0], acc[nt]);
                acc[nt] = mfma16(fH1, BihH[nt][1], acc[nt]);
                acc[nt] = mfma16(fH0, BihL[nt][0], acc[nt]);
                acc[nt] = mfma16(fH1, BihL[nt][1], acc[nt]);
                acc[nt] = mfma16(fL0, BihH[nt][0], acc[nt]);
                acc[nt] = mfma16(fL1, BihH[nt][1], acc[nt]);
            }
        }
        __syncthreads();   // staging visible

        // ---- recurrent MFMAs over this wave's K-half (conflict-free b128) ----
        {
            const char* sH = (const char*)&stg[0][0] + hf * 16384 + q * 256 + n15 * 16;
            const char* sL = (const char*)&stg[1][0] + hf * 16384 + q * 256 + n15 * 16;
#pragma unroll
            for (int kt = 0; kt < 16; kt++) {
                f16x8 ah = __builtin_bit_cast(f16x8, *(const u32x4*)(sH + kt * 1024));
                f16x8 al = __builtin_bit_cast(f16x8, *(const u32x4*)(sL + kt * 1024));
#pragma unroll
                for (int nt = 0; nt < 4; nt++) {
                    acc[nt] = mfma16(ah, Bhh[nt][kt], acc[nt]);
                    acc[nt] = mfma16(al, Bhh[nt][kt], acc[nt]);
                }
            }
#pragma unroll
            for (int nt = 0; nt < 4; nt++)
                *(f32x4*)(&gbuf[hf * 2560 + (rg * 64 + nt * 16 + n15) * 20 + q * 4]) = acc[nt];
        }
        __syncthreads();

        // ---- elementwise LSTM cell (fp32), 2 pairs per thread ----
        float xi0 = gbuf[a0]        + gbuf[2560 + a0]        + bias0[0];
        float xf0 = gbuf[a0 + 640]  + gbuf[2560 + a0 + 640]  + bias0[1];
        float xg0 = gbuf[a0 + 1280] + gbuf[2560 + a0 + 1280] + bias0[2];
        float xo0 = gbuf[a0 + 1920] + gbuf[2560 + a0 + 1920] + bias0[3];
        c0 = sigm(xf0) * c0 + sigm(xi0) * tanhf(xg0);
        float h0v = sigm(xo0) * tanhf(c0);

        float xi1 = gbuf[a0 + 20]        + gbuf[2560 + a0 + 20]        + bias1[0];
        float xf1 = gbuf[a0 + 20 + 640]  + gbuf[2560 + a0 + 20 + 640]  + bias1[1];
        float xg1 = gbuf[a0 + 20 + 1280] + gbuf[2560 + a0 + 20 + 1280] + bias1[2];
        float xo1 = gbuf[a0 + 20 + 1920] + gbuf[2560 + a0 + 20 + 1920] + bias1[3];
        c1 = sigm(xf1) * c1 + sigm(xi1) * tanhf(xg1);
        float h1v = sigm(xo1) * tanhf(c1);

        if (t == NPAST - 1) {   // boundary: h0 = h_p + temb, c0 = c_p + temb
            float t0 = temb[(size_t)gb * HID + U0];
            float t1 = temb[(size_t)gb * HID + U0 + 1];
            h0v += t0; c0 += t0;
            h1v += t1; c1 += t1;
        }
        if (t >= NPAST) {       // future pass: store fp32 h for head
            float* hp = hfut + ((size_t)(t - NPAST) * BATCH + gb) * HID;
            hp[U0]     = h0v;
            hp[U0 + 1] = h1v;
        }

        // ---- publish new h (hi/lo fp16): sc0 (SE-scope) stores -> XCD L2 ----
        {
            f16_t h0h = (f16_t)h0v; f16_t h0l = (f16_t)(h0v - (float)h0h);
            f16_t h1h = (f16_t)h1v; f16_t h1l = (f16_t)(h1v - (float)h1h);
            uint32_t ph = (uint32_t)__builtin_bit_cast(uint16_t, h0h)
                        | ((uint32_t)__builtin_bit_cast(uint16_t, h1h) << 16);
            uint32_t pl = (uint32_t)__builtin_bit_cast(uint16_t, h0l)
                        | ((uint32_t)__builtin_bit_cast(uint16_t, h1l) << 16);
            f16_t* dst = hbuf + (size_t)((t + 1) & 1) * HPAR + (size_t)g * GSLAB + stOff;
            asm volatile("global_store_dword %0, %2, off sc0\n\t"
                         "global_store_dword %1, %3, off sc0\n\t"
                         "s_waitcnt vmcnt(0)"       // drain: h visible in XCD L2
                         :: "v"(dst), "v"(dst + HPLN), "v"(ph), "v"(pl)
                         : "memory");
        }

        // ---- per-group flag barrier: proven device-scope (sc1) path ----
        __syncthreads();   // all threads' h stores drained above
        if (tid == 0)
            asm volatile("global_store_dword %0, %1, off sc1"
                         :: "v"(&gflags[m]), "v"((uint32_t)(t + 1)) : "memory");
        if (w == 0) {      // wave 0 polls all 32 member flags via sc1 (MALL)
            uint32_t tgt = (uint32_t)(t + 1);
            const uint32_t* fp = &gflags[lane & 31];
            int guard = 0;
            for (;;) {
                uint32_t v;
                asm volatile("global_load_dword %0, %1, off sc1\n\t"
                             "s_waitcnt vmcnt(0)"
                             : "=v"(v) : "v"(fp) : "memory");
                if (lane >= 32) v = tgt;
                if (__all(v >= tgt)) break;
                if (++guard > (1 << 20)) break;   // never hang on claim failure
            }
        }
        __syncthreads();
    }
}

// ---------------- epilogue: head out[b,s] = h . Wh + bh ----------------
__global__ __launch_bounds__(256)
void head(const float* __restrict__ hfut, const float* __restrict__ Wh,
          const float* __restrict__ bh, float* __restrict__ out)
{
    int b = blockIdx.x >> 3, s = blockIdx.x & 7;
    int tid = threadIdx.x;
    const float* h = hfut + ((size_t)s * BATCH + b) * HID;
    float4 hv = *(const float4*)(h + tid * 4);
    float4 wv = *(const float4*)(Wh + tid * 4);
    float p = hv.x * wv.x + hv.y * wv.y + hv.z * wv.z + hv.w * wv.w;
#pragma unroll
    for (int off = 32; off > 0; off >>= 1) p += __shfl_down(p, off);
    __shared__ float r[4];
    if ((tid & 63) == 0) r[tid >> 6] = p;
    __syncthreads();
    if (tid == 0) out[b * HHOR + s] = r[0] + r[1] + r[2] + r[3] + bh[0];
}

extern "C" void kernel_launch(void* const* d_in, const int* in_sizes, int n_in,
                              void* d_out, int out_size, void* d_ws, size_t ws_size,
                              hipStream_t stream)
{
    const float* x_past = (const float*)d_in[0];
    const float* noisy  = (const float*)d_in[1];
    const float* tv     = (const float*)d_in[2];
    const float* x_fut  = (const float*)d_in[3];
    const float* statc  = (const float*)d_in[4];
    const float* W_ih   = (const float*)d_in[5];
    const float* W_hh   = (const float*)d_in[6];
    const float* b_ih   = (const float*)d_in[7];
    const float* b_hh   = (const float*)d_in[8];
    const float* freqs  = (const float*)d_in[9];
    const float* phases = (const float*)d_in[10];
    const float* W1     = (const float*)d_in[11];
    const float* b1     = (const float*)d_in[12];
    const float* W2     = (const float*)d_in[13];
    const float* b2     = (const float*)d_in[14];
    const float* Wh     = (const float*)d_in[15];
    const float* bh     = (const float*)d_in[16];
    float* out = (float*)d_out;

    char* ws = (char*)d_ws;
    const size_t sz_feats = (size_t)2 * BATCH * TSTEPS * KF * 2;   // 2 planes
    const size_t off_temb = sz_feats;
    const size_t sz_temb  = (size_t)BATCH * HID * 4;
    const size_t off_hbuf = off_temb + sz_temb;
    const size_t sz_hbuf  = (size_t)2 * HPAR * 2;                  // 2 parities
    const size_t off_hfut = off_hbuf + sz_hbuf;
    const size_t sz_hfut  = (size_t)HHOR * BATCH * HID * 4;
    const size_t off_flag = off_hfut + sz_hfut;

    f16_t*    feats = (f16_t*)(ws);
    float*    temb  = (float*)(ws + off_temb);
    f16_t*    hbuf  = (f16_t*)(ws + off_hbuf);
    float*    hfut  = (float*)(ws + off_hfut);
    uint32_t* flags = (uint32_t*)(ws + off_flag);
    int*      cnts  = (int*)(flags + NGRP * CUPG);    // 8 claim counters

    // zero h parity-0 (both planes), flags, and claim counters.
    hipMemsetAsync(hbuf, 0, (size_t)HPAR * 2, stream);
    hipMemsetAsync(flags, 0, (size_t)(NGRP * CUPG + NGRP) * sizeof(uint32_t), stream);

    build_feats<<<(BATCH * TSTEPS * KF) / 256, 256, 0, stream>>>(x_past, noisy, x_fut, statc, feats);
    time_mlp<<<BATCH, 256, 0, stream>>>(tv, freqs, phases, W1, b1, W2, b2, temb);
    lstm_persist<<<NGRP * CUPG, 256, 0, stream>>>(feats, temb, hbuf, hfut, flags, cnts,
                                                  W_ih, W_hh, b_ih, b_hh);
    head<<<BATCH * HHOR, 256, 0, stream>>>(hfut, Wh, bh, out);
}